// Round 1
// baseline (510.095 us; speedup 1.0000x reference)
//
#include <hip/hip_runtime.h>
#include <cstddef>
#include <cmath>

// Problem constants (from reference)
#define BATCH 2
#define CIN 3
#define H 48
#define KS 5
#define KN 16
#define OW 44               // H - KS + 1
#define P 1936              // OW*OW patches
#define F 75                // CIN*KS*KS
#define MU_OUT_SIZE (BATCH*KN*P)   // 61952

// ---------------------------------------------------------------------------
// Kernel 1: build xmT[b][f][q]  (q contiguous so sigma kernel q-loads coalesce)
// xmT[b][f][q] = mu_in[b][c][qy+kh][qx+kw],  f=(c,kh,kw), q=qy*44+qx
// ---------------------------------------------------------------------------
__global__ void build_patches(const float* __restrict__ mu_in,
                              float* __restrict__ xmT) {
    int idx = blockIdx.x * 256 + threadIdx.x;
    if (idx >= BATCH * F * P) return;
    int q = idx % P;
    int f = (idx / P) % F;
    int b = idx / (F * P);
    int c  = f / (KS * KS);
    int r  = f % (KS * KS);
    int kh = r / KS, kw = r % KS;
    int qy = q / OW, qx = q % OW;
    xmT[idx] = mu_in[((b * CIN + c) * H + (qy + kh)) * H + (qx + kw)];
}

// ---------------------------------------------------------------------------
// Kernel 2: mean path — direct 5x5 valid conv, weights in LDS
// out[b][n][p] ,  p = py*44+px
// ---------------------------------------------------------------------------
__global__ void conv_mu(const float* __restrict__ mu_in,
                        const float* __restrict__ w_mu,
                        float* __restrict__ out) {
    __shared__ float wsh[KN * F];
    for (int i = threadIdx.x; i < KN * F; i += 256) wsh[i] = w_mu[i];
    __syncthreads();
    int idx = blockIdx.x * 256 + threadIdx.x;
    if (idx >= MU_OUT_SIZE) return;
    int p = idx % P;
    int n = (idx / P) % KN;
    int b = idx / (P * KN);
    int py = p / OW, px = p % OW;
    const float* img = mu_in + b * CIN * H * H;
    const float* w   = wsh + n * F;
    float acc = 0.f;
#pragma unroll
    for (int c = 0; c < CIN; c++)
#pragma unroll
        for (int kh = 0; kh < KS; kh++)
#pragma unroll
            for (int kw = 0; kw < KS; kw++)
                acc += img[(c * H + py + kh) * H + (px + kw)] *
                       w[c * KS * KS + kh * KS + kw];
    out[idx] = acc;
}

// ---------------------------------------------------------------------------
// Kernel 3: sigma[b][n][p][q] = dot_f(xm[p], xm[q]) * softplus(w_sigma[n])
// Block: 256 threads = one (b, 8-p tile, 1024-q tile).
// Each thread owns 4 consecutive q (float4), accumulates acc[8][4],
// then writes 8p x 16n float4 stores (all coalesced dwordx4).
// ---------------------------------------------------------------------------
#define TP 8
#define TQ 1024
#define NQB 2               // ceil(1936/1024)

__global__ void sigma_kernel(const float* __restrict__ xmT,
                             const float* __restrict__ w_sigma,
                             float* __restrict__ out) {
    int bid = blockIdx.x;
    int qb  = bid % NQB;
    int pt  = (bid / NQB) % (P / TP);
    int b   = bid / (NQB * (P / TP));
    int tid = threadIdx.x;
    int p0  = pt * TP;
    int q0  = qb * TQ + tid * 4;

    __shared__ float xp[TP][F + 1];
    __shared__ float sp[KN];

    for (int i = tid; i < TP * F; i += 256) {
        int pp = i / F, f = i % F;
        xp[pp][f] = xmT[((size_t)b * F + f) * P + (p0 + pp)];
    }
    if (tid < KN) sp[tid] = log1pf(expf(w_sigma[tid]));
    __syncthreads();

    if (q0 >= P) return;   // tail q-tile (P%4==0, q0%4==0 so q0..q0+3 all valid)

    float acc[TP][4];
#pragma unroll
    for (int pp = 0; pp < TP; pp++)
#pragma unroll
        for (int j = 0; j < 4; j++) acc[pp][j] = 0.f;

    const float* xq_base = xmT + (size_t)b * F * P + q0;
    for (int f = 0; f < F; f++) {
        float4 xq = *(const float4*)(xq_base + (size_t)f * P);
#pragma unroll
        for (int pp = 0; pp < TP; pp++) {
            float xpv = xp[pp][f];
            acc[pp][0] += xpv * xq.x;
            acc[pp][1] += xpv * xq.y;
            acc[pp][2] += xpv * xq.z;
            acc[pp][3] += xpv * xq.w;
        }
    }

    float* sig = out + MU_OUT_SIZE;
#pragma unroll
    for (int n = 0; n < KN; n++) {
        float s = sp[n];
#pragma unroll
        for (int pp = 0; pp < TP; pp++) {
            size_t o = (((size_t)(b * KN + n)) * P + (p0 + pp)) * P + q0;
            float4 v = make_float4(acc[pp][0] * s, acc[pp][1] * s,
                                   acc[pp][2] * s, acc[pp][3] * s);
            *(float4*)(sig + o) = v;
        }
    }
}

// ---------------------------------------------------------------------------
extern "C" void kernel_launch(void* const* d_in, const int* in_sizes, int n_in,
                              void* d_out, int out_size, void* d_ws, size_t ws_size,
                              hipStream_t stream) {
    const float* mu_in   = (const float*)d_in[0];
    const float* w_mu    = (const float*)d_in[1];
    const float* w_sigma = (const float*)d_in[2];
    float* out = (float*)d_out;
    float* xmT = (float*)d_ws;   // needs B*F*P*4 = 1,161,600 bytes

    build_patches<<<(BATCH * F * P + 255) / 256, 256, 0, stream>>>(mu_in, xmT);
    conv_mu<<<(MU_OUT_SIZE + 255) / 256, 256, 0, stream>>>(mu_in, w_mu, out);
    sigma_kernel<<<BATCH * (P / TP) * NQB, 256, 0, stream>>>(xmT, w_sigma, out);
}